// Round 7
// baseline (75.926 us; speedup 1.0000x reference)
//
#include <hip/hip_runtime.h>
#include <math.h>

// Problem constants (match reference)
#define BTC   64      // B*T
#define NJ    20      // J
#define KSEL  300     // K
#define NCROP 2048
#define NFULL 16384
#define DOBJ  256
#define DEMB  64
#define DJF   64
#define RAD2  (0.025f*0.025f)

// ---------------- Kernel 1: objfeat + joints + IK (one block per bt) -------
// 1024 threads: quad q = t>>8 handles 512 points for all 256 channels (t&255)
__global__ __launch_bounds__(1024) void k_joints(
    const float* __restrict__ traj,      // (BT,9)
    const float* __restrict__ obj_crop,  // (BT,2048,6)
    const float* __restrict__ W_obj,     // (6,256)
    const float* __restrict__ b_obj,     // (256)
    const float* __restrict__ W_init,    // (265,60)
    const float* __restrict__ b_init,    // (60)
    const float* __restrict__ tmpl,      // (21,3)
    float* __restrict__ out_joints,      // d_out[0:3840]
    float* __restrict__ ws_joints,       // (1280,3)
    float* __restrict__ ws_R,            // (1280,9)
    float* __restrict__ ws_Rinv,         // (1280,9)
    float* __restrict__ ws_tinv)         // (1280,3)
{
    const int bt = blockIdx.x;
    const int t  = threadIdx.x;
    const int q  = t >> 8;
    const int ch = t & 255;

    __shared__ float pts[4][128 * 8];   // 16 KB (points padded to 8 floats)
    __shared__ float red[4 * 256];      // 4 KB
    __shared__ float feat[272];
    __shared__ float jarr[60];

    float wo[6];
#pragma unroll
    for (int i = 0; i < 6; ++i) wo[i] = W_obj[i * DOBJ + ch];
    const float bo = b_obj[ch];

    const float* base = obj_crop + (size_t)bt * NCROP * 6;
    float mx = 0.0f;  // relu >= 0 => equivalent to -inf init
    for (int k = 0; k < 4; ++k) {
        const float* src = base + (size_t)((q * 4 + k) * 128) * 6;
#pragma unroll
        for (int i = 0; i < 3; ++i) {
            const int idx = i * 256 + ch;
            pts[q][(idx / 6) * 8 + (idx % 6)] = src[idx];
        }
        __syncthreads();
#pragma unroll 8
        for (int p = 0; p < 128; ++p) {
            const float4 lo = *(const float4*)(&pts[q][p * 8]);
            const float2 hi = *(const float2*)(&pts[q][p * 8 + 4]);
            float acc = bo;
            acc += lo.x * wo[0]; acc += lo.y * wo[1]; acc += lo.z * wo[2];
            acc += lo.w * wo[3]; acc += hi.x * wo[4]; acc += hi.y * wo[5];
            mx = fmaxf(mx, fmaxf(acc, 0.0f));
        }
        __syncthreads();
    }
    red[q * 256 + ch] = mx;
    __syncthreads();

    if (t < 256) {
        float m4 = fmaxf(fmaxf(red[t], red[256 + t]),
                         fmaxf(red[512 + t], red[768 + t]));
        feat[9 + t] = m4;
        if (t < 9) feat[t] = traj[bt * 9 + t];
    }
    __syncthreads();

    // matvec (265 -> 60), 4 lanes per output channel
    if (t < 240) {
        const int o = t >> 2, r = t & 3;
        float acc = 0.0f;
        for (int i = r; i < 9 + DOBJ; i += 4) acc += feat[i] * W_init[i * 60 + o];
        acc += __shfl_xor(acc, 1);
        acc += __shfl_xor(acc, 2);
        if (r == 0) jarr[o] = acc + b_init[o];
    }
    __syncthreads();

    if (t < 60) {
        out_joints[bt * 60 + t] = jarr[t];
        ws_joints[bt * 60 + t]  = jarr[t];
    }

    if (t < NJ) {
        const int j   = t;
        const int gid = bt * NJ + j;
        const float eps = 1e-8f;
        float bx0 = jarr[j * 3 + 0];
        float by0 = jarr[j * 3 + 1];
        float bz0 = jarr[j * 3 + 2];
        float ax0 = tmpl[(j + 1) * 3 + 0] - tmpl[0];
        float ay0 = tmpl[(j + 1) * 3 + 1] - tmpl[1];
        float az0 = tmpl[(j + 1) * 3 + 2] - tmpl[2];

        float ia = 1.0f / (sqrtf(ax0 * ax0 + ay0 * ay0 + az0 * az0) + eps);
        float ax = ax0 * ia, ay = ay0 * ia, az = az0 * ia;
        float ib = 1.0f / (sqrtf(bx0 * bx0 + by0 * by0 + bz0 * bz0) + eps);
        float bx = bx0 * ib, by = by0 * ib, bz = bz0 * ib;

        float vx = ay * bz - az * by;
        float vy = az * bx - ax * bz;
        float vz = ax * by - ay * bx;
        float cc = ax * bx + ay * by + az * bz;
        float s2 = vx * vx + vy * vy + vz * vz;

        float R[9];
        if (s2 < eps) {
            R[0]=1; R[1]=0; R[2]=0; R[3]=0; R[4]=1; R[5]=0; R[6]=0; R[7]=0; R[8]=1;
        } else {
            float coef = (1.0f - cc) / (s2 + eps);
            R[0] = 1.0f + coef * (-(vy * vy + vz * vz));
            R[1] = -vz  + coef * (vx * vy);
            R[2] =  vy  + coef * (vx * vz);
            R[3] =  vz  + coef * (vx * vy);
            R[4] = 1.0f + coef * (-(vx * vx + vz * vz));
            R[5] = -vx  + coef * (vy * vz);
            R[6] = -vy  + coef * (vx * vz);
            R[7] =  vx  + coef * (vy * vz);
            R[8] = 1.0f + coef * (-(vx * vx + vy * vy));
        }
        float tx = bx0 - (R[0] * ax0 + R[1] * ay0 + R[2] * az0);
        float ty = by0 - (R[3] * ax0 + R[4] * ay0 + R[5] * az0);
        float tz = bz0 - (R[6] * ax0 + R[7] * ay0 + R[8] * az0);

        float det = R[0] * (R[4] * R[8] - R[5] * R[7])
                  - R[1] * (R[3] * R[8] - R[5] * R[6])
                  + R[2] * (R[3] * R[7] - R[4] * R[6]);
        float id = 1.0f / det;
        float Ri[9];
        Ri[0] = (R[4] * R[8] - R[5] * R[7]) * id;
        Ri[1] = (R[2] * R[7] - R[1] * R[8]) * id;
        Ri[2] = (R[1] * R[5] - R[2] * R[4]) * id;
        Ri[3] = (R[5] * R[6] - R[3] * R[8]) * id;
        Ri[4] = (R[0] * R[8] - R[2] * R[6]) * id;
        Ri[5] = (R[2] * R[3] - R[0] * R[5]) * id;
        Ri[6] = (R[3] * R[7] - R[4] * R[6]) * id;
        Ri[7] = (R[1] * R[6] - R[0] * R[7]) * id;
        Ri[8] = (R[0] * R[4] - R[1] * R[3]) * id;

        float tix = -(Ri[0] * tx + Ri[1] * ty + Ri[2] * tz);
        float tiy = -(Ri[3] * tx + Ri[4] * ty + Ri[5] * tz);
        float tiz = -(Ri[6] * tx + Ri[7] * ty + Ri[8] * tz);

#pragma unroll
        for (int i = 0; i < 9; ++i) ws_R[gid * 9 + i] = R[i];
#pragma unroll
        for (int i = 0; i < 9; ++i) ws_Rinv[gid * 9 + i] = Ri[i];
        ws_tinv[gid * 3 + 0] = tix;
        ws_tinv[gid * 3 + 1] = tiy;
        ws_tinv[gid * 3 + 2] = tiz;
    }
}

// ---------------- Kernel 2: ball-query masks (register-direct, no LDS pts) --
// grid = BTC*32; block (bt, blkc) tests 512 points vs all 20 joints
__global__ __launch_bounds__(256) void k_ballmask(
    const float* __restrict__ obj_full,  // (BT,16384,6)
    const float* __restrict__ ws_joints, // (1280,3)
    unsigned long long* __restrict__ ws_mask) // (BT*NJ,256)
{
    const int bt   = blockIdx.x >> 5;
    const int blkc = blockIdx.x & 31;
    const int t    = threadIdx.x;
    const int lane = t & 63;
    const int wv   = t >> 6;

    __shared__ unsigned long long lmask[NJ][8];   // 1.25 KB

    // joints are block-uniform -> scalar (SGPR) broadcast loads
    float jx[NJ], jy[NJ], jz[NJ];
    const float* jp = ws_joints + bt * NJ * 3;
#pragma unroll
    for (int j = 0; j < NJ; ++j) {
        jx[j] = jp[j * 3 + 0];
        jy[j] = jp[j * 3 + 1];
        jz[j] = jp[j * 3 + 2];
    }

    const float* blk = obj_full + ((size_t)bt * NFULL + blkc * 512) * 6;
#pragma unroll
    for (int it = 0; it < 2; ++it) {
        const float* p = blk + (size_t)(it * 256 + t) * 6;
        const float2 xy = *(const float2*)p;   // 8B-aligned (24B record)
        const float  pz = p[2];
        const float px = xy.x, py = xy.y;
        const int word = it * 4 + wv;
#pragma unroll
        for (int j = 0; j < NJ; ++j) {
            float dx = px - jx[j], dy = py - jy[j], dz = pz - jz[j];
            bool within = (dx * dx + dy * dy + dz * dz) < RAD2;
            unsigned long long m = __ballot(within);
            if (lane == 0) lmask[j][word] = m;
        }
    }
    __syncthreads();

    // coalesced mask store: 160 u64 per block
    if (t < NJ * 8) {
        const int j = t >> 3, w = t & 7;
        ws_mask[(size_t)(bt * NJ + j) * 256 + blkc * 8 + w] = lmask[j][w];
    }
}

// ------- Kernel 3: select + canonicalize + jf max-pool + disp head -------
// one block per (bt, j), 256 threads
__global__ __launch_bounds__(256) void k_ballq_disp(
    const float* __restrict__ obj_full,  // (BT,16384,6)
    const unsigned long long* __restrict__ ws_mask, // (BT*NJ,256)
    const float* __restrict__ ws_joints, // (1280,3)
    const float* __restrict__ ws_R,      // (1280,9)
    const float* __restrict__ ws_Rinv,   // (1280,9)
    const float* __restrict__ ws_tinv,   // (1280,3)
    const float* __restrict__ W_jf,      // (6,64)
    const float* __restrict__ b_jf,      // (64)
    const float* __restrict__ W_emb,     // (3,64)
    const float* __restrict__ b_emb,     // (64)
    const float* __restrict__ W_st,      // (128,3)
    float* __restrict__ out)             // d_out (disp at 3840)
{
    const int pair = blockIdx.x;           // bt*20 + j
    const int bt   = pair / NJ;
    const int t    = threadIdx.x;
    const int lane = t & 63;
    const int wv   = t >> 6;

    __shared__ float sel[KSEL * 6];
    __shared__ int   wsum[4];
    __shared__ float red[256];

    const float qx = ws_joints[pair * 3 + 0];
    const float qy = ws_joints[pair * 3 + 1];
    const float qz = ws_joints[pair * 3 + 2];
    float Ri[9];
#pragma unroll
    for (int i = 0; i < 9; ++i) Ri[i] = ws_Rinv[pair * 9 + i];
    const float tix = ws_tinv[pair * 3 + 0];
    const float tiy = ws_tinv[pair * 3 + 1];
    const float tiz = ws_tinv[pair * 3 + 2];

    const float* pts = obj_full + (size_t)bt * NFULL * 6;

    // ---- phase 1: load my 64-point mask word (coalesced 2 KB) ----
    unsigned long long myw = ws_mask[(size_t)pair * 256 + t];

    // ---- phase 2: exact prefix ranks over 256 words ----
    int cnt = __popcll(myw);
    int incl = cnt;
#pragma unroll
    for (int o = 1; o < 64; o <<= 1) {
        int v = __shfl_up(incl, o);
        if (lane >= o) incl += v;
    }
    if (lane == 63) wsum[wv] = incl;
    __syncthreads();
    int wbase = 0;
    for (int w = 0; w < wv; ++w) wbase += wsum[w];
    const int excl = wbase + incl - cnt;
    const int total = wsum[0] + wsum[1] + wsum[2] + wsum[3];

    // ---- phase 3: compaction (index order), canonicalize into LDS ----
    if (excl < KSEL && cnt > 0) {
        unsigned long long m = myw;
        int r = excl;
        while (m && r < KSEL) {
            int b = __ffsll((long long)m) - 1;
            m &= m - 1;
            const float* p = pts + (size_t)(t * 64 + b) * 6;
            float px = p[0], py = p[1], pz = p[2];
            float nx = p[3], ny = p[4], nz = p[5];
            sel[r * 6 + 0] = Ri[0] * px + Ri[1] * py + Ri[2] * pz + tix;
            sel[r * 6 + 1] = Ri[3] * px + Ri[4] * py + Ri[5] * pz + tiy;
            sel[r * 6 + 2] = Ri[6] * px + Ri[7] * py + Ri[8] * pz + tiz;
            sel[r * 6 + 3] = Ri[0] * nx + Ri[1] * ny + Ri[2] * nz;
            sel[r * 6 + 4] = Ri[3] * nx + Ri[4] * ny + Ri[5] * nz;
            sel[r * 6 + 5] = Ri[6] * nx + Ri[7] * ny + Ri[8] * nz;
            ++r;
        }
    }
    __syncthreads();

    // ---- phase 4: jf = max over selected of relu(sp@W_jf+b) ----
    const int n   = total < KSEL ? total : KSEL;
    const int chn = t & 63;     // channel
    const int sl  = t >> 6;     // slice 0..3
    float wj[6];
#pragma unroll
    for (int i = 0; i < 6; ++i) wj[i] = W_jf[i * DJF + chn];
    const float bj = b_jf[chn];

    float acc = 0.0f;  // relu>=0; empty -> 0 matches where(isfinite) semantics
    for (int p = sl; p < n; p += 4) {
        float v = bj;
#pragma unroll
        for (int i = 0; i < 6; ++i) v += sel[p * 6 + i] * wj[i];
        acc = fmaxf(acc, fmaxf(v, 0.0f));
    }
    red[t] = acc;
    __syncthreads();

    // ---- phase 5: disp head ----
    if (t < 64) {
        float mm = fmaxf(fmaxf(red[t], red[t + 64]),
                         fmaxf(red[t + 128], red[t + 192]));
        float e = b_emb[t] + qx * W_emb[t] + qy * W_emb[64 + t] + qz * W_emb[128 + t];
        float g0 = e * W_st[t * 3 + 0] + mm * W_st[(64 + t) * 3 + 0];
        float g1 = e * W_st[t * 3 + 1] + mm * W_st[(64 + t) * 3 + 1];
        float g2 = e * W_st[t * 3 + 2] + mm * W_st[(64 + t) * 3 + 2];
#pragma unroll
        for (int o = 32; o > 0; o >>= 1) {
            g0 += __shfl_xor(g0, o);
            g1 += __shfl_xor(g1, o);
            g2 += __shfl_xor(g2, o);
        }
        if (t == 0) {
            const float* R = ws_R + pair * 9;
            // disp - joints_init + jcano cancels exactly => just R@g
            out[3840 + pair * 3 + 0] = R[0] * g0 + R[1] * g1 + R[2] * g2;
            out[3840 + pair * 3 + 1] = R[3] * g0 + R[4] * g1 + R[5] * g2;
            out[3840 + pair * 3 + 2] = R[6] * g0 + R[7] * g1 + R[8] * g2;
        }
    }
}

extern "C" void kernel_launch(void* const* d_in, const int* in_sizes, int n_in,
                              void* d_out, int out_size, void* d_ws, size_t ws_size,
                              hipStream_t stream) {
    const float* rhand_traj = (const float*)d_in[0];
    const float* obj_crop   = (const float*)d_in[1];
    const float* obj_full   = (const float*)d_in[2];
    const float* tmpl       = (const float*)d_in[3];
    const float* W_obj      = (const float*)d_in[4];
    const float* b_obj      = (const float*)d_in[5];
    const float* W_init     = (const float*)d_in[6];
    const float* b_init     = (const float*)d_in[7];
    const float* W_emb      = (const float*)d_in[8];
    const float* b_emb      = (const float*)d_in[9];
    const float* W_jf       = (const float*)d_in[10];
    const float* b_jf       = (const float*)d_in[11];
    const float* W_st       = (const float*)d_in[12];
    float* out = (float*)d_out;

    // workspace layout (floats; mask array 8-byte aligned: 30720*4 % 8 == 0)
    float* ws = (float*)d_ws;
    float* ws_joints = ws;                   // 3840
    float* ws_R      = ws + 3840;            // 11520
    float* ws_Rinv   = ws + 15360;           // 11520
    float* ws_tinv   = ws + 26880;           // 3840
    unsigned long long* ws_mask =
        (unsigned long long*)(ws + 30720);   // 1280*256 u64 = 2.62 MB

    k_joints<<<BTC, 1024, 0, stream>>>(rhand_traj, obj_crop, W_obj, b_obj,
                                       W_init, b_init, tmpl, out, ws_joints,
                                       ws_R, ws_Rinv, ws_tinv);
    k_ballmask<<<BTC * 32, 256, 0, stream>>>(obj_full, ws_joints, ws_mask);
    k_ballq_disp<<<BTC * NJ, 256, 0, stream>>>(obj_full, ws_mask, ws_joints,
                                               ws_R, ws_Rinv, ws_tinv,
                                               W_jf, b_jf, W_emb, b_emb, W_st, out);
}

// Round 8
// 37.849 us; speedup vs baseline: 2.0061x; 2.0061x over previous
//
#include <hip/hip_runtime.h>
#include <math.h>

// Problem constants (match reference)
#define BTC   64      // B*T
#define NJ    20      // J
#define KSEL  300     // K
#define NCROP 2048
#define NFULL 16384
#define DOBJ  256
#define DEMB  64
#define DJF   64
#define RAD2  (0.025f*0.025f)

// ---------------- Kernel A1: partial obj-feat max ----------------
// grid = BTC*16; block (bt, ch) handles 128 points, 256 threads = channels
__global__ __launch_bounds__(256) void k_objfeat_part(
    const float* __restrict__ obj_crop,  // (BT,2048,6)
    const float* __restrict__ W_obj,     // (6,256)
    const float* __restrict__ b_obj,     // (256)
    float* __restrict__ ws_partial)      // (BT,16,256)
{
    const int bt = blockIdx.x >> 4;
    const int ch = blockIdx.x & 15;
    const int t  = threadIdx.x;
    __shared__ float lds_pts[128 * 8];   // 4 KB, point-padded to 8 floats

    float wo[6];
#pragma unroll
    for (int i = 0; i < 6; ++i) wo[i] = W_obj[i * DOBJ + t];
    const float bo = b_obj[t];

    const float* base = obj_crop + (size_t)bt * NCROP * 6 + ch * 768;
#pragma unroll
    for (int i = 0; i < 3; ++i) {
        const int idx = i * 256 + t;         // 768 floats in the chunk
        lds_pts[(idx / 6) * 8 + (idx % 6)] = base[idx];
    }
    __syncthreads();

    float mx = 0.0f;  // relu >= 0 => equivalent to -inf init
#pragma unroll 8
    for (int p = 0; p < 128; ++p) {
        const float4 lo = *(const float4*)(lds_pts + p * 8);
        const float2 hi = *(const float2*)(lds_pts + p * 8 + 4);
        float acc = bo;
        acc += lo.x * wo[0]; acc += lo.y * wo[1]; acc += lo.z * wo[2];
        acc += lo.w * wo[3]; acc += hi.x * wo[4]; acc += hi.y * wo[5];
        mx = fmaxf(mx, fmaxf(acc, 0.0f));
    }
    ws_partial[(bt * 16 + ch) * 256 + t] = mx;
}

// ---------------- Kernel A2: reduce + joints + IK ----------------
// grid = BTC, 256 threads. Matvec fully unrolled -> ~66 independent loads.
__global__ __launch_bounds__(256) void k_joints_ik(
    const float* __restrict__ ws_partial, // (BT,16,256)
    const float* __restrict__ traj,       // (BT,9)
    const float* __restrict__ W_init,     // (265,60)
    const float* __restrict__ b_init,     // (60)
    const float* __restrict__ tmpl,       // (21,3)
    float* __restrict__ out_joints,       // d_out[0:3840]
    float* __restrict__ ws_joints,        // (1280,3)
    float* __restrict__ ws_R,             // (1280,9)
    float* __restrict__ ws_Rinv,          // (1280,9)
    float* __restrict__ ws_tinv)          // (1280,3)
{
    const int bt = blockIdx.x;
    const int t  = threadIdx.x;
    __shared__ float feat[272];
    __shared__ float jarr[60];

    const float* pp = ws_partial + bt * 16 * 256 + t;
    float mx = pp[0];
#pragma unroll
    for (int c = 1; c < 16; ++c) mx = fmaxf(mx, pp[c * 256]);
    feat[9 + t] = mx;
    if (t < 9) feat[t] = traj[bt * 9 + t];
    __syncthreads();

    // matvec (265 -> 60), 4 lanes per output; COMPILE-TIME trip count so the
    // 66 W_init loads issue independently (no serial load->use chain).
    if (t < 240) {
        const int o = t >> 2, r = t & 3;
        float acc = 0.0f;
#pragma unroll
        for (int m = 0; m < 66; ++m) {
            const int i = r + 4 * m;        // <= 263, always valid
            acc += feat[i] * W_init[i * 60 + o];
        }
        if (r == 0) acc += feat[264] * W_init[264 * 60 + o];  // tail (265=66*4+1)
        acc += __shfl_xor(acc, 1);
        acc += __shfl_xor(acc, 2);
        if (r == 0) jarr[o] = acc + b_init[o];
    }
    __syncthreads();

    if (t < 60) {
        out_joints[bt * 60 + t] = jarr[t];
        ws_joints[bt * 60 + t]  = jarr[t];
    }

    if (t < NJ) {
        const int j   = t;
        const int gid = bt * NJ + j;
        const float eps = 1e-8f;
        float bx0 = jarr[j * 3 + 0];
        float by0 = jarr[j * 3 + 1];
        float bz0 = jarr[j * 3 + 2];
        float ax0 = tmpl[(j + 1) * 3 + 0] - tmpl[0];
        float ay0 = tmpl[(j + 1) * 3 + 1] - tmpl[1];
        float az0 = tmpl[(j + 1) * 3 + 2] - tmpl[2];

        float ia = 1.0f / (sqrtf(ax0 * ax0 + ay0 * ay0 + az0 * az0) + eps);
        float ax = ax0 * ia, ay = ay0 * ia, az = az0 * ia;
        float ib = 1.0f / (sqrtf(bx0 * bx0 + by0 * by0 + bz0 * bz0) + eps);
        float bx = bx0 * ib, by = by0 * ib, bz = bz0 * ib;

        float vx = ay * bz - az * by;
        float vy = az * bx - ax * bz;
        float vz = ax * by - ay * bx;
        float cc = ax * bx + ay * by + az * bz;
        float s2 = vx * vx + vy * vy + vz * vz;

        float R[9];
        if (s2 < eps) {
            R[0]=1; R[1]=0; R[2]=0; R[3]=0; R[4]=1; R[5]=0; R[6]=0; R[7]=0; R[8]=1;
        } else {
            float coef = (1.0f - cc) / (s2 + eps);
            R[0] = 1.0f + coef * (-(vy * vy + vz * vz));
            R[1] = -vz  + coef * (vx * vy);
            R[2] =  vy  + coef * (vx * vz);
            R[3] =  vz  + coef * (vx * vy);
            R[4] = 1.0f + coef * (-(vx * vx + vz * vz));
            R[5] = -vx  + coef * (vy * vz);
            R[6] = -vy  + coef * (vx * vz);
            R[7] =  vx  + coef * (vy * vz);
            R[8] = 1.0f + coef * (-(vx * vx + vy * vy));
        }
        float tx = bx0 - (R[0] * ax0 + R[1] * ay0 + R[2] * az0);
        float ty = by0 - (R[3] * ax0 + R[4] * ay0 + R[5] * az0);
        float tz = bz0 - (R[6] * ax0 + R[7] * ay0 + R[8] * az0);

        float det = R[0] * (R[4] * R[8] - R[5] * R[7])
                  - R[1] * (R[3] * R[8] - R[5] * R[6])
                  + R[2] * (R[3] * R[7] - R[4] * R[6]);
        float id = 1.0f / det;
        float Ri[9];
        Ri[0] = (R[4] * R[8] - R[5] * R[7]) * id;
        Ri[1] = (R[2] * R[7] - R[1] * R[8]) * id;
        Ri[2] = (R[1] * R[5] - R[2] * R[4]) * id;
        Ri[3] = (R[5] * R[6] - R[3] * R[8]) * id;
        Ri[4] = (R[0] * R[8] - R[2] * R[6]) * id;
        Ri[5] = (R[2] * R[3] - R[0] * R[5]) * id;
        Ri[6] = (R[3] * R[7] - R[4] * R[6]) * id;
        Ri[7] = (R[1] * R[6] - R[0] * R[7]) * id;
        Ri[8] = (R[0] * R[4] - R[1] * R[3]) * id;

        float tix = -(Ri[0] * tx + Ri[1] * ty + Ri[2] * tz);
        float tiy = -(Ri[3] * tx + Ri[4] * ty + Ri[5] * tz);
        float tiz = -(Ri[6] * tx + Ri[7] * ty + Ri[8] * tz);

#pragma unroll
        for (int i = 0; i < 9; ++i) ws_R[gid * 9 + i] = R[i];
#pragma unroll
        for (int i = 0; i < 9; ++i) ws_Rinv[gid * 9 + i] = Ri[i];
        ws_tinv[gid * 3 + 0] = tix;
        ws_tinv[gid * 3 + 1] = tiy;
        ws_tinv[gid * 3 + 2] = tiz;
    }
}

// ---------------- Kernel C1: ball-query masks (register-direct) ------------
// grid = BTC*32; block (bt, blkc) tests 512 points vs all 20 joints
__global__ __launch_bounds__(256) void k_ballmask(
    const float* __restrict__ obj_full,  // (BT,16384,6)
    const float* __restrict__ ws_joints, // (1280,3)
    unsigned long long* __restrict__ ws_mask) // (BT*NJ,256)
{
    const int bt   = blockIdx.x >> 5;
    const int blkc = blockIdx.x & 31;
    const int t    = threadIdx.x;
    const int lane = t & 63;
    const int wv   = t >> 6;

    __shared__ unsigned long long lmask[NJ][8];   // 1.25 KB

    // joints are block-uniform -> scalar broadcast loads
    float jx[NJ], jy[NJ], jz[NJ];
    const float* jp = ws_joints + bt * NJ * 3;
#pragma unroll
    for (int j = 0; j < NJ; ++j) {
        jx[j] = jp[j * 3 + 0];
        jy[j] = jp[j * 3 + 1];
        jz[j] = jp[j * 3 + 2];
    }

    const float* blk = obj_full + ((size_t)bt * NFULL + blkc * 512) * 6;
#pragma unroll
    for (int it = 0; it < 2; ++it) {
        const float* p = blk + (size_t)(it * 256 + t) * 6;
        const float2 xy = *(const float2*)p;   // 8B-aligned (24B record)
        const float  pz = p[2];
        const float px = xy.x, py = xy.y;
        const int word = it * 4 + wv;
#pragma unroll
        for (int j = 0; j < NJ; ++j) {
            float dx = px - jx[j], dy = py - jy[j], dz = pz - jz[j];
            bool within = (dx * dx + dy * dy + dz * dz) < RAD2;
            unsigned long long m = __ballot(within);
            if (lane == 0) lmask[j][word] = m;
        }
    }
    __syncthreads();

    // coalesced mask store: 160 u64 per block
    if (t < NJ * 8) {
        const int j = t >> 3, w = t & 7;
        ws_mask[(size_t)(bt * NJ + j) * 256 + blkc * 8 + w] = lmask[j][w];
    }
}

// ------- Kernel C2: select + canonicalize + jf max-pool + disp head -------
// one block per (bt, j), 256 threads
__global__ __launch_bounds__(256) void k_ballq_disp(
    const float* __restrict__ obj_full,  // (BT,16384,6)
    const unsigned long long* __restrict__ ws_mask, // (BT*NJ,256)
    const float* __restrict__ ws_joints, // (1280,3)
    const float* __restrict__ ws_R,      // (1280,9)
    const float* __restrict__ ws_Rinv,   // (1280,9)
    const float* __restrict__ ws_tinv,   // (1280,3)
    const float* __restrict__ W_jf,      // (6,64)
    const float* __restrict__ b_jf,      // (64)
    const float* __restrict__ W_emb,     // (3,64)
    const float* __restrict__ b_emb,     // (64)
    const float* __restrict__ W_st,      // (128,3)
    float* __restrict__ out)             // d_out (disp at 3840)
{
    const int pair = blockIdx.x;           // bt*20 + j
    const int bt   = pair / NJ;
    const int t    = threadIdx.x;
    const int lane = t & 63;
    const int wv   = t >> 6;

    __shared__ float sel[KSEL * 6];
    __shared__ int   wsum[4];
    __shared__ float red[256];

    const float qx = ws_joints[pair * 3 + 0];
    const float qy = ws_joints[pair * 3 + 1];
    const float qz = ws_joints[pair * 3 + 2];
    float Ri[9];
#pragma unroll
    for (int i = 0; i < 9; ++i) Ri[i] = ws_Rinv[pair * 9 + i];
    const float tix = ws_tinv[pair * 3 + 0];
    const float tiy = ws_tinv[pair * 3 + 1];
    const float tiz = ws_tinv[pair * 3 + 2];

    const float* pts = obj_full + (size_t)bt * NFULL * 6;

    // ---- phase 1: load my 64-point mask word (coalesced 2 KB) ----
    unsigned long long myw = ws_mask[(size_t)pair * 256 + t];

    // ---- phase 2: exact prefix ranks over 256 words ----
    int cnt = __popcll(myw);
    int incl = cnt;
#pragma unroll
    for (int o = 1; o < 64; o <<= 1) {
        int v = __shfl_up(incl, o);
        if (lane >= o) incl += v;
    }
    if (lane == 63) wsum[wv] = incl;
    __syncthreads();
    int wbase = 0;
    for (int w = 0; w < wv; ++w) wbase += wsum[w];
    const int excl = wbase + incl - cnt;
    const int total = wsum[0] + wsum[1] + wsum[2] + wsum[3];

    // ---- phase 3: compaction (index order), canonicalize into LDS ----
    if (excl < KSEL && cnt > 0) {
        unsigned long long m = myw;
        int r = excl;
        while (m && r < KSEL) {
            int b = __ffsll((long long)m) - 1;
            m &= m - 1;
            const float* p = pts + (size_t)(t * 64 + b) * 6;
            float px = p[0], py = p[1], pz = p[2];
            float nx = p[3], ny = p[4], nz = p[5];
            sel[r * 6 + 0] = Ri[0] * px + Ri[1] * py + Ri[2] * pz + tix;
            sel[r * 6 + 1] = Ri[3] * px + Ri[4] * py + Ri[5] * pz + tiy;
            sel[r * 6 + 2] = Ri[6] * px + Ri[7] * py + Ri[8] * pz + tiz;
            sel[r * 6 + 3] = Ri[0] * nx + Ri[1] * ny + Ri[2] * nz;
            sel[r * 6 + 4] = Ri[3] * nx + Ri[4] * ny + Ri[5] * nz;
            sel[r * 6 + 5] = Ri[6] * nx + Ri[7] * ny + Ri[8] * nz;
            ++r;
        }
    }
    __syncthreads();

    // ---- phase 4: jf = max over selected of relu(sp@W_jf+b) ----
    const int n   = total < KSEL ? total : KSEL;
    const int chn = t & 63;     // channel
    const int sl  = t >> 6;     // slice 0..3
    float wj[6];
#pragma unroll
    for (int i = 0; i < 6; ++i) wj[i] = W_jf[i * DJF + chn];
    const float bj = b_jf[chn];

    float acc = 0.0f;  // relu>=0; empty -> 0 matches where(isfinite) semantics
    for (int p = sl; p < n; p += 4) {
        float v = bj;
#pragma unroll
        for (int i = 0; i < 6; ++i) v += sel[p * 6 + i] * wj[i];
        acc = fmaxf(acc, fmaxf(v, 0.0f));
    }
    red[t] = acc;
    __syncthreads();

    // ---- phase 5: disp head ----
    if (t < 64) {
        float mm = fmaxf(fmaxf(red[t], red[t + 64]),
                         fmaxf(red[t + 128], red[t + 192]));
        float e = b_emb[t] + qx * W_emb[t] + qy * W_emb[64 + t] + qz * W_emb[128 + t];
        float g0 = e * W_st[t * 3 + 0] + mm * W_st[(64 + t) * 3 + 0];
        float g1 = e * W_st[t * 3 + 1] + mm * W_st[(64 + t) * 3 + 1];
        float g2 = e * W_st[t * 3 + 2] + mm * W_st[(64 + t) * 3 + 2];
#pragma unroll
        for (int o = 32; o > 0; o >>= 1) {
            g0 += __shfl_xor(g0, o);
            g1 += __shfl_xor(g1, o);
            g2 += __shfl_xor(g2, o);
        }
        if (t == 0) {
            const float* R = ws_R + pair * 9;
            // disp - joints_init + jcano cancels exactly => just R@g
            out[3840 + pair * 3 + 0] = R[0] * g0 + R[1] * g1 + R[2] * g2;
            out[3840 + pair * 3 + 1] = R[3] * g0 + R[4] * g1 + R[5] * g2;
            out[3840 + pair * 3 + 2] = R[6] * g0 + R[7] * g1 + R[8] * g2;
        }
    }
}

extern "C" void kernel_launch(void* const* d_in, const int* in_sizes, int n_in,
                              void* d_out, int out_size, void* d_ws, size_t ws_size,
                              hipStream_t stream) {
    const float* rhand_traj = (const float*)d_in[0];
    const float* obj_crop   = (const float*)d_in[1];
    const float* obj_full   = (const float*)d_in[2];
    const float* tmpl       = (const float*)d_in[3];
    const float* W_obj      = (const float*)d_in[4];
    const float* b_obj      = (const float*)d_in[5];
    const float* W_init     = (const float*)d_in[6];
    const float* b_init     = (const float*)d_in[7];
    const float* W_emb      = (const float*)d_in[8];
    const float* b_emb      = (const float*)d_in[9];
    const float* W_jf       = (const float*)d_in[10];
    const float* b_jf       = (const float*)d_in[11];
    const float* W_st       = (const float*)d_in[12];
    float* out = (float*)d_out;

    // workspace layout (floats; mask array 8-byte aligned)
    float* ws = (float*)d_ws;
    float* ws_partial = ws;                  // 64*16*256 = 262144
    float* ws_joints  = ws + 262144;         // 3840
    float* ws_R       = ws + 265984;         // 11520
    float* ws_Rinv    = ws + 277504;         // 11520
    float* ws_tinv    = ws + 289024;         // 3840
    unsigned long long* ws_mask =
        (unsigned long long*)(ws + 292864);  // 1280*256 u64 = 2.62 MB

    k_objfeat_part<<<BTC * 16, 256, 0, stream>>>(obj_crop, W_obj, b_obj, ws_partial);
    k_joints_ik<<<BTC, 256, 0, stream>>>(ws_partial, rhand_traj, W_init, b_init,
                                         tmpl, out, ws_joints,
                                         ws_R, ws_Rinv, ws_tinv);
    k_ballmask<<<BTC * 32, 256, 0, stream>>>(obj_full, ws_joints, ws_mask);
    k_ballq_disp<<<BTC * NJ, 256, 0, stream>>>(obj_full, ws_mask, ws_joints,
                                               ws_R, ws_Rinv, ws_tinv,
                                               W_jf, b_jf, W_emb, b_emb, W_st, out);
}